// Round 3
// baseline (632.362 us; speedup 1.0000x reference)
//
#include <hip/hip_runtime.h>
#include <math.h>

#define N_ENTITY 64368
#define N_REL 12
#define DIM 128
#define NB 8
#define N_ITEM 6924
#define NEDGE 1000000
#define BATCH 128
#define SEQL 32
#define ITEM_TILE 32

// padded sizes (workspace layout)
#define CNT_PAD 64384     // >= N_ENTITY, 16-aligned
#define OFFS_PAD 64400    // >= N_ENTITY+1

// ---------------------------------------------------------------------------
// Phase 1a: count kept edges (dst < N_ITEM) per SRC.  ~1.67 edges per used
// src -> negligible atomic contention (unlike per-dst: 144 per counter).
// ---------------------------------------------------------------------------
__global__ __launch_bounds__(256) void count_kernel(
    const int* __restrict__ e_src, const int* __restrict__ e_dst,
    int* __restrict__ cnt)
{
    int gid = blockIdx.x * 256 + threadIdx.x;
    if (gid < NEDGE) {
        if (e_dst[gid] < N_ITEM) atomicAdd(&cnt[e_src[gid]], 1);
    }
}

// ---------------------------------------------------------------------------
// Phase 1b: exclusive scan over cnt[N_ENTITY].  Single block, 1024 threads,
// 63 elems/thread (two serial passes over L2-resident cnt; no reg pressure),
// Hillis-Steele over 1024 partials in LDS.
// ---------------------------------------------------------------------------
#define SCAN_C 63   // 1024*63 = 64512 >= N_ENTITY
__global__ __launch_bounds__(1024) void scan_kernel(
    const int* __restrict__ cnt, int* __restrict__ offs, int* __restrict__ cursor)
{
    __shared__ int part[1024];
    int tid = threadIdx.x;
    int s = 0;
    for (int i = 0; i < SCAN_C; ++i) {
        int idx = tid * SCAN_C + i;
        s += (idx < N_ENTITY) ? cnt[idx] : 0;
    }
    part[tid] = s;
    __syncthreads();
    for (int off = 1; off < 1024; off <<= 1) {
        int v = (tid >= off) ? part[tid - off] : 0;
        __syncthreads();
        part[tid] += v;
        __syncthreads();
    }
    int run = (tid == 0) ? 0 : part[tid - 1];
    for (int i = 0; i < SCAN_C; ++i) {
        int idx = tid * SCAN_C + i;
        if (idx < N_ENTITY) {
            offs[idx] = run; cursor[idx] = run;
            run += cnt[idx];
        }
    }
    if (tid == 1023) offs[N_ENTITY] = part[1023];
}

// ---------------------------------------------------------------------------
// Phase 1c: scatter kept edges into SRC buckets as packed dst|type<<13
// (dst < 6924 < 2^13, type < 12).  Also counts deg per dst (107.6k cheap
// int atomics).
// ---------------------------------------------------------------------------
__global__ __launch_bounds__(256) void fill_kernel(
    const int* __restrict__ e_src, const int* __restrict__ e_dst,
    const int* __restrict__ e_type, int* __restrict__ cursor,
    int* __restrict__ bucket, float* __restrict__ deg)
{
    int gid = blockIdx.x * 256 + threadIdx.x;
    if (gid < NEDGE) {
        int d = e_dst[gid];
        if (d < N_ITEM) {
            int s = e_src[gid];
            int pos = atomicAdd(&cursor[s], 1);
            bucket[pos] = d | (e_type[gid] << 13);
            atomicAdd(&deg[d], 1.0f);
        }
    }
}

// ---------------------------------------------------------------------------
// Phase 2: SRC-major aggregation.  One wave per src entity: read the src's
// 8 basis rows ONCE (ascending src order -> near-streaming HBM traffic,
// ~215 MB total vs 441 MB random in the dst-major version), then for each
// outgoing kept edge combine with att[type] in registers and atomicAdd the
// 128-d message into L2-resident aggr[dst].  Empty srcs exit before any
// basis load.
// ---------------------------------------------------------------------------
__global__ __launch_bounds__(256) void aggregate_kernel(
    const int* __restrict__ offs, const int* __restrict__ bucket,
    const float* __restrict__ basis, const float* __restrict__ att,
    float* __restrict__ aggr)
{
    __shared__ float att_s[N_REL * NB];
    if (threadIdx.x < N_REL * NB) att_s[threadIdx.x] = att[threadIdx.x];
    __syncthreads();

    int wave = threadIdx.x >> 6;
    int lane = threadIdx.x & 63;
    int src  = blockIdx.x * 4 + wave;
    if (src >= N_ENTITY) return;

    int o0 = offs[src], o1 = offs[src + 1];
    if (o0 == o1) return;

    // load this src's 8 basis rows: lane covers dims {2*lane, 2*lane+1}
    const float* bp = basis + (size_t)src * DIM + lane * 2;
    float2 row[NB];
    #pragma unroll
    for (int b = 0; b < NB; ++b)
        row[b] = *reinterpret_cast<const float2*>(bp + (size_t)b * (N_ENTITY * DIM));

    for (int j = o0; j < o1; ++j) {
        int p = bucket[j];          // same address all lanes -> broadcast
        int d = p & 8191;
        int t = p >> 13;
        float mx = 0.f, my = 0.f;
        #pragma unroll
        for (int b = 0; b < NB; ++b) {
            float a = att_s[t * NB + b];
            mx += a * row[b].x;
            my += a * row[b].y;
        }
        float* outp = aggr + (size_t)d * DIM + lane * 2;
        atomicAdd(outp,     mx);
        atomicAdd(outp + 1, my);
    }
}

// ---------------------------------------------------------------------------
// Phase 3: nodes[n,:] = aggr[n,:]/max(deg[n],1) + root[n,:] + bias  (n < N_ITEM)
// ---------------------------------------------------------------------------
__global__ __launch_bounds__(256) void finalize_kernel(
    const float* __restrict__ aggr, const float* __restrict__ deg,
    const float* __restrict__ root, const float* __restrict__ bias,
    float* __restrict__ nodes)
{
    int idx = blockIdx.x * 256 + threadIdx.x;   // one float4 per thread
    if (idx >= N_ITEM * (DIM / 4)) return;
    int n  = idx >> 5;
    int kq = idx & 31;
    float inv = 1.0f / fmaxf(deg[n], 1.0f);
    float4 a  = reinterpret_cast<const float4*>(aggr)[idx];
    float4 r  = reinterpret_cast<const float4*>(root)[idx];
    float4 bs = reinterpret_cast<const float4*>(bias)[kq];
    float4 o;
    o.x = a.x * inv + r.x + bs.x;
    o.y = a.y * inv + r.y + bs.y;
    o.z = a.z * inv + r.z + bs.z;
    o.w = a.w * inv + r.w + bs.w;
    reinterpret_cast<float4*>(nodes)[idx] = o;
}

// ---------------------------------------------------------------------------
// Phase 4: attention pool.  One block per batch row.
// ---------------------------------------------------------------------------
__global__ __launch_bounds__(256) void pool_kernel(
    const float* __restrict__ nodes, const int* __restrict__ seed_ids,
    const int* __restrict__ seed_len, const float* __restrict__ attn_a,
    const float* __restrict__ attn_b, float* __restrict__ u)
{
    __shared__ float h[SEQL * 132];
    __shared__ float ev[SEQL];
    __shared__ float attw[SEQL];
    __shared__ int   seeds[SEQL];

    int b   = blockIdx.x;
    int tid = threadIdx.x;
    int len = seed_len[b];

    if (tid < SEQL) seeds[tid] = seed_ids[b * SEQL + tid];
    __syncthreads();

    for (int idx = tid; idx < SEQL * (DIM / 4); idx += 256) {
        int l  = idx >> 5;
        int kq = idx & 31;
        float4 v = reinterpret_cast<const float4*>(nodes)[(size_t)seeds[l] * 32 + kq];
        *reinterpret_cast<float4*>(h + l * 132 + kq * 4) = v;
    }
    __syncthreads();

    {
        int l = tid >> 3;
        int j = tid & 7;
        float dot[16];
        #pragma unroll
        for (int i = 0; i < 16; ++i) dot[i] = 0.f;
        const float* hr = h + l * 132;
        for (int k = 0; k < DIM; ++k) {
            float hv = hr[k];
            const float4* ar = reinterpret_cast<const float4*>(attn_a + k * DIM + j * 16);
            float4 a0 = ar[0], a1 = ar[1], a2 = ar[2], a3 = ar[3];
            dot[0]  += hv * a0.x; dot[1]  += hv * a0.y; dot[2]  += hv * a0.z; dot[3]  += hv * a0.w;
            dot[4]  += hv * a1.x; dot[5]  += hv * a1.y; dot[6]  += hv * a1.z; dot[7]  += hv * a1.w;
            dot[8]  += hv * a2.x; dot[9]  += hv * a2.y; dot[10] += hv * a2.z; dot[11] += hv * a2.w;
            dot[12] += hv * a3.x; dot[13] += hv * a3.y; dot[14] += hv * a3.z; dot[15] += hv * a3.w;
        }
        float sum = 0.f;
        #pragma unroll
        for (int i = 0; i < 16; ++i) sum += tanhf(dot[i]) * attn_b[j * 16 + i];
        sum += __shfl_xor(sum, 1);
        sum += __shfl_xor(sum, 2);
        sum += __shfl_xor(sum, 4);
        if (j == 0) ev[l] = sum;
    }
    __syncthreads();

    if (tid < SEQL) {
        float val = (tid < len) ? ev[tid] : -3.0e38f;
        float m = val;
        #pragma unroll
        for (int off = 16; off > 0; off >>= 1) m = fmaxf(m, __shfl_xor(m, off));
        float p = (tid < len) ? expf(val - m) : 0.f;
        float ssum = p;
        #pragma unroll
        for (int off = 16; off > 0; off >>= 1) ssum += __shfl_xor(ssum, off);
        attw[tid] = (len > 0) ? p / ssum : 0.f;
    }
    __syncthreads();

    if (tid < DIM) {
        float acc = 0.f;
        #pragma unroll
        for (int l = 0; l < SEQL; ++l) acc += attw[l] * h[l * 132 + tid];
        u[(size_t)b * DIM + tid] = acc;
    }
}

// ---------------------------------------------------------------------------
// Phase 5: scores[b,i] = u[b,:] . nodes[i,:] + out_bias[i]
// ---------------------------------------------------------------------------
__global__ __launch_bounds__(256) void score_kernel(
    const float* __restrict__ nodes, const float* __restrict__ u,
    const float* __restrict__ out_bias, float* __restrict__ out)
{
    __shared__ float us[BATCH * DIM];
    __shared__ float ns[ITEM_TILE * 132];
    int tid   = threadIdx.x;
    int item0 = blockIdx.x * ITEM_TILE;

    for (int idx = tid; idx < BATCH * (DIM / 4); idx += 256)
        reinterpret_cast<float4*>(us)[idx] = reinterpret_cast<const float4*>(u)[idx];

    for (int idx = tid; idx < ITEM_TILE * (DIM / 4); idx += 256) {
        int j  = idx >> 5;
        int kq = idx & 31;
        int item = item0 + j;
        float4 v = make_float4(0.f, 0.f, 0.f, 0.f);
        if (item < N_ITEM) v = reinterpret_cast<const float4*>(nodes)[(size_t)item * 32 + kq];
        *reinterpret_cast<float4*>(ns + j * 132 + kq * 4) = v;
    }
    __syncthreads();

    int jg = tid & 15;
    int bg = tid >> 4;
    float acc0[8], acc1[8];
    #pragma unroll
    for (int i = 0; i < 8; ++i) { acc0[i] = 0.f; acc1[i] = 0.f; }
    const float* n0p = ns + (jg * 2 + 0) * 132;
    const float* n1p = ns + (jg * 2 + 1) * 132;
    for (int k = 0; k < DIM; k += 4) {
        float4 n0 = *reinterpret_cast<const float4*>(n0p + k);
        float4 n1 = *reinterpret_cast<const float4*>(n1p + k);
        #pragma unroll
        for (int bb = 0; bb < 8; ++bb) {
            float4 uv = *reinterpret_cast<const float4*>(us + (bg * 8 + bb) * DIM + k);
            acc0[bb] += uv.x * n0.x + uv.y * n0.y + uv.z * n0.z + uv.w * n0.w;
            acc1[bb] += uv.x * n1.x + uv.y * n1.y + uv.z * n1.z + uv.w * n1.w;
        }
    }
    #pragma unroll
    for (int bb = 0; bb < 8; ++bb) {
        int bi  = bg * 8 + bb;
        int it0 = item0 + jg * 2;
        if (it0     < N_ITEM) out[(size_t)bi * N_ITEM + it0]     = acc0[bb] + out_bias[it0];
        if (it0 + 1 < N_ITEM) out[(size_t)bi * N_ITEM + it0 + 1] = acc1[bb] + out_bias[it0 + 1];
    }
}

extern "C" void kernel_launch(void* const* d_in, const int* in_sizes, int n_in,
                              void* d_out, int out_size, void* d_ws, size_t ws_size,
                              hipStream_t stream)
{
    const int*   e_src     = (const int*)d_in[0];          // edge_idx[0]
    const int*   e_dst     = e_src + NEDGE;                // edge_idx[1]
    const int*   e_type    = (const int*)d_in[1];
    const int*   seed_ids  = (const int*)d_in[2];
    const int*   seed_len  = (const int*)d_in[3];
    // d_in[4] = labels (unused by reference)
    const float* basis     = (const float*)d_in[5];
    const float* att       = (const float*)d_in[6];
    const float* root      = (const float*)d_in[7];
    const float* rgcn_bias = (const float*)d_in[8];
    const float* attn_a    = (const float*)d_in[9];
    const float* attn_b    = (const float*)d_in[10];
    const float* out_bias  = (const float*)d_in[11];
    float*       out       = (float*)d_out;

    // workspace layout: [cnt | aggr | deg]=memset-region, offs, cursor,
    // bucket, nodes, u   (~12 MB total)
    int*   cnt    = (int*)d_ws;
    float* aggr   = (float*)(cnt + CNT_PAD);
    float* deg    = aggr + (size_t)N_ITEM * DIM;
    int*   offs   = (int*)(deg + 6928);
    int*   cursor = offs + OFFS_PAD;
    int*   bucket = cursor + OFFS_PAD;
    float* nodes  = (float*)(bucket + NEDGE);
    float* u      = nodes + (size_t)N_ITEM * DIM;

    hipMemsetAsync(cnt, 0, (CNT_PAD + (size_t)N_ITEM * DIM + 6928) * sizeof(int), stream);

    count_kernel<<<(NEDGE + 255) / 256, 256, 0, stream>>>(e_src, e_dst, cnt);
    scan_kernel<<<1, 1024, 0, stream>>>(cnt, offs, cursor);
    fill_kernel<<<(NEDGE + 255) / 256, 256, 0, stream>>>(
        e_src, e_dst, e_type, cursor, bucket, deg);
    aggregate_kernel<<<(N_ENTITY + 3) / 4, 256, 0, stream>>>(
        offs, bucket, basis, att, aggr);
    finalize_kernel<<<(N_ITEM * (DIM / 4) + 255) / 256, 256, 0, stream>>>(
        aggr, deg, root, rgcn_bias, nodes);
    pool_kernel<<<BATCH, 256, 0, stream>>>(
        nodes, seed_ids, seed_len, attn_a, attn_b, u);
    score_kernel<<<(N_ITEM + ITEM_TILE - 1) / ITEM_TILE, 256, 0, stream>>>(
        nodes, u, out_bias, out);
}

// Round 4
// 495.254 us; speedup vs baseline: 1.2768x; 1.2768x over previous
//
#include <hip/hip_runtime.h>
#include <math.h>

#define N_ENTITY 64368
#define N_REL 12
#define DIM 128
#define NB 8
#define N_ITEM 6924
#define NEDGE 1000000
#define BATCH 128
#define SEQL 32
#define ITEM_TILE 32

#define CNT_PAD 64384     // >= N_ENTITY, 16-aligned
#define OFFS_PAD 64400    // >= N_ENTITY+1

// ---------------------------------------------------------------------------
// Phase 1a: count kept edges (dst < N_ITEM) per SRC.  ~1.67 edges per used
// src -> negligible atomic contention.
// ---------------------------------------------------------------------------
__global__ __launch_bounds__(256) void count_kernel(
    const int* __restrict__ e_src, const int* __restrict__ e_dst,
    int* __restrict__ cnt)
{
    int gid = blockIdx.x * 256 + threadIdx.x;
    if (gid < NEDGE) {
        if (e_dst[gid] < N_ITEM) atomicAdd(&cnt[e_src[gid]], 1);
    }
}

// ---------------------------------------------------------------------------
// Phase 1b: bucket-offset ALLOCATION (replaces the 159us single-block scan).
// Buckets need to be disjoint, not ordered: each wave prefix-scans 64 cnt
// values in-register, lane 63 bumps one global cursor once, lanes write
// offs = base + prefix.  ~1006 atomics total, fully parallel.
// ---------------------------------------------------------------------------
__global__ __launch_bounds__(256) void alloc_kernel(
    const int* __restrict__ cnt, int* __restrict__ gcursor,
    int* __restrict__ offs, int* __restrict__ cursor)
{
    int idx  = blockIdx.x * 256 + threadIdx.x;
    int lane = threadIdx.x & 63;
    int c = (idx < N_ENTITY) ? cnt[idx] : 0;
    int pre = c;                       // inclusive wave prefix
    #pragma unroll
    for (int off = 1; off < 64; off <<= 1) {
        int v = __shfl_up(pre, off);
        if (lane >= off) pre += v;
    }
    int total = __shfl(pre, 63);
    int base = 0;
    if (lane == 63) base = atomicAdd(gcursor, total);
    base = __shfl(base, 63);
    if (idx < N_ENTITY) {
        int o = base + pre - c;        // exclusive
        offs[idx]   = o;
        cursor[idx] = o;
    }
}

// ---------------------------------------------------------------------------
// Phase 1c: scatter kept edges into SRC buckets as packed dst|type<<13
// (dst < 6924 < 2^13, type < 12).  Also counts deg per dst.
// ---------------------------------------------------------------------------
__global__ __launch_bounds__(256) void fill_kernel(
    const int* __restrict__ e_src, const int* __restrict__ e_dst,
    const int* __restrict__ e_type, int* __restrict__ cursor,
    int* __restrict__ bucket, float* __restrict__ deg)
{
    int gid = blockIdx.x * 256 + threadIdx.x;
    if (gid < NEDGE) {
        int d = e_dst[gid];
        if (d < N_ITEM) {
            int s = e_src[gid];
            int pos = atomicAdd(&cursor[s], 1);
            bucket[pos] = d | (e_type[gid] << 13);
            atomicAdd(&deg[d], 1.0f);
        }
    }
}

// ---------------------------------------------------------------------------
// Phase 2: SRC-major aggregation.  One wave per src entity: read the src's
// 8 basis rows ONCE (~215 MB total streaming vs 441 MB random dst-major),
// combine per outgoing edge with att[type] in registers, atomicAdd the
// 128-d message into L2-resident aggr[dst].  Empty srcs exit early.
// ---------------------------------------------------------------------------
__global__ __launch_bounds__(256) void aggregate_kernel(
    const int* __restrict__ offs, const int* __restrict__ cnt,
    const int* __restrict__ bucket, const float* __restrict__ basis,
    const float* __restrict__ att, float* __restrict__ aggr)
{
    __shared__ float att_s[N_REL * NB];
    if (threadIdx.x < N_REL * NB) att_s[threadIdx.x] = att[threadIdx.x];
    __syncthreads();

    int wave = threadIdx.x >> 6;
    int lane = threadIdx.x & 63;
    int src  = blockIdx.x * 4 + wave;
    if (src >= N_ENTITY) return;

    int n = cnt[src];
    if (n == 0) return;
    int o0 = offs[src], o1 = o0 + n;

    const float* bp = basis + (size_t)src * DIM + lane * 2;
    float2 row[NB];
    #pragma unroll
    for (int b = 0; b < NB; ++b)
        row[b] = *reinterpret_cast<const float2*>(bp + (size_t)b * (N_ENTITY * DIM));

    for (int j = o0; j < o1; ++j) {
        int p = bucket[j];             // same address all lanes -> broadcast
        int d = p & 8191;
        int t = p >> 13;
        float mx = 0.f, my = 0.f;
        #pragma unroll
        for (int b = 0; b < NB; ++b) {
            float a = att_s[t * NB + b];
            mx += a * row[b].x;
            my += a * row[b].y;
        }
        float* outp = aggr + (size_t)d * DIM + lane * 2;
        atomicAdd(outp,     mx);
        atomicAdd(outp + 1, my);
    }
}

// ---------------------------------------------------------------------------
// Phase 3: nodes[n,:] = aggr[n,:]/max(deg[n],1) + root[n,:] + bias  (n < N_ITEM)
// ---------------------------------------------------------------------------
__global__ __launch_bounds__(256) void finalize_kernel(
    const float* __restrict__ aggr, const float* __restrict__ deg,
    const float* __restrict__ root, const float* __restrict__ bias,
    float* __restrict__ nodes)
{
    int idx = blockIdx.x * 256 + threadIdx.x;
    if (idx >= N_ITEM * (DIM / 4)) return;
    int n  = idx >> 5;
    int kq = idx & 31;
    float inv = 1.0f / fmaxf(deg[n], 1.0f);
    float4 a  = reinterpret_cast<const float4*>(aggr)[idx];
    float4 r  = reinterpret_cast<const float4*>(root)[idx];
    float4 bs = reinterpret_cast<const float4*>(bias)[kq];
    float4 o;
    o.x = a.x * inv + r.x + bs.x;
    o.y = a.y * inv + r.y + bs.y;
    o.z = a.z * inv + r.z + bs.z;
    o.w = a.w * inv + r.w + bs.w;
    reinterpret_cast<float4*>(nodes)[idx] = o;
}

// ---------------------------------------------------------------------------
// Phase 4: attention pool.  One block per batch row.
// ---------------------------------------------------------------------------
__global__ __launch_bounds__(256) void pool_kernel(
    const float* __restrict__ nodes, const int* __restrict__ seed_ids,
    const int* __restrict__ seed_len, const float* __restrict__ attn_a,
    const float* __restrict__ attn_b, float* __restrict__ u)
{
    __shared__ float h[SEQL * 132];
    __shared__ float ev[SEQL];
    __shared__ float attw[SEQL];
    __shared__ int   seeds[SEQL];

    int b   = blockIdx.x;
    int tid = threadIdx.x;
    int len = seed_len[b];

    if (tid < SEQL) seeds[tid] = seed_ids[b * SEQL + tid];
    __syncthreads();

    for (int idx = tid; idx < SEQL * (DIM / 4); idx += 256) {
        int l  = idx >> 5;
        int kq = idx & 31;
        float4 v = reinterpret_cast<const float4*>(nodes)[(size_t)seeds[l] * 32 + kq];
        *reinterpret_cast<float4*>(h + l * 132 + kq * 4) = v;
    }
    __syncthreads();

    {
        int l = tid >> 3;
        int j = tid & 7;
        float dot[16];
        #pragma unroll
        for (int i = 0; i < 16; ++i) dot[i] = 0.f;
        const float* hr = h + l * 132;
        for (int k = 0; k < DIM; ++k) {
            float hv = hr[k];
            const float4* ar = reinterpret_cast<const float4*>(attn_a + k * DIM + j * 16);
            float4 a0 = ar[0], a1 = ar[1], a2 = ar[2], a3 = ar[3];
            dot[0]  += hv * a0.x; dot[1]  += hv * a0.y; dot[2]  += hv * a0.z; dot[3]  += hv * a0.w;
            dot[4]  += hv * a1.x; dot[5]  += hv * a1.y; dot[6]  += hv * a1.z; dot[7]  += hv * a1.w;
            dot[8]  += hv * a2.x; dot[9]  += hv * a2.y; dot[10] += hv * a2.z; dot[11] += hv * a2.w;
            dot[12] += hv * a3.x; dot[13] += hv * a3.y; dot[14] += hv * a3.z; dot[15] += hv * a3.w;
        }
        float sum = 0.f;
        #pragma unroll
        for (int i = 0; i < 16; ++i) sum += tanhf(dot[i]) * attn_b[j * 16 + i];
        sum += __shfl_xor(sum, 1);
        sum += __shfl_xor(sum, 2);
        sum += __shfl_xor(sum, 4);
        if (j == 0) ev[l] = sum;
    }
    __syncthreads();

    if (tid < SEQL) {
        float val = (tid < len) ? ev[tid] : -3.0e38f;
        float m = val;
        #pragma unroll
        for (int off = 16; off > 0; off >>= 1) m = fmaxf(m, __shfl_xor(m, off));
        float p = (tid < len) ? expf(val - m) : 0.f;
        float ssum = p;
        #pragma unroll
        for (int off = 16; off > 0; off >>= 1) ssum += __shfl_xor(ssum, off);
        attw[tid] = (len > 0) ? p / ssum : 0.f;
    }
    __syncthreads();

    if (tid < DIM) {
        float acc = 0.f;
        #pragma unroll
        for (int l = 0; l < SEQL; ++l) acc += attw[l] * h[l * 132 + tid];
        u[(size_t)b * DIM + tid] = acc;
    }
}

// ---------------------------------------------------------------------------
// Phase 5: scores[b,i] = u[b,:] . nodes[i,:] + out_bias[i]
// ---------------------------------------------------------------------------
__global__ __launch_bounds__(256) void score_kernel(
    const float* __restrict__ nodes, const float* __restrict__ u,
    const float* __restrict__ out_bias, float* __restrict__ out)
{
    __shared__ float us[BATCH * DIM];
    __shared__ float ns[ITEM_TILE * 132];
    int tid   = threadIdx.x;
    int item0 = blockIdx.x * ITEM_TILE;

    for (int idx = tid; idx < BATCH * (DIM / 4); idx += 256)
        reinterpret_cast<float4*>(us)[idx] = reinterpret_cast<const float4*>(u)[idx];

    for (int idx = tid; idx < ITEM_TILE * (DIM / 4); idx += 256) {
        int j  = idx >> 5;
        int kq = idx & 31;
        int item = item0 + j;
        float4 v = make_float4(0.f, 0.f, 0.f, 0.f);
        if (item < N_ITEM) v = reinterpret_cast<const float4*>(nodes)[(size_t)item * 32 + kq];
        *reinterpret_cast<float4*>(ns + j * 132 + kq * 4) = v;
    }
    __syncthreads();

    int jg = tid & 15;
    int bg = tid >> 4;
    float acc0[8], acc1[8];
    #pragma unroll
    for (int i = 0; i < 8; ++i) { acc0[i] = 0.f; acc1[i] = 0.f; }
    const float* n0p = ns + (jg * 2 + 0) * 132;
    const float* n1p = ns + (jg * 2 + 1) * 132;
    for (int k = 0; k < DIM; k += 4) {
        float4 n0 = *reinterpret_cast<const float4*>(n0p + k);
        float4 n1 = *reinterpret_cast<const float4*>(n1p + k);
        #pragma unroll
        for (int bb = 0; bb < 8; ++bb) {
            float4 uv = *reinterpret_cast<const float4*>(us + (bg * 8 + bb) * DIM + k);
            acc0[bb] += uv.x * n0.x + uv.y * n0.y + uv.z * n0.z + uv.w * n0.w;
            acc1[bb] += uv.x * n1.x + uv.y * n1.y + uv.z * n1.z + uv.w * n1.w;
        }
    }
    #pragma unroll
    for (int bb = 0; bb < 8; ++bb) {
        int bi  = bg * 8 + bb;
        int it0 = item0 + jg * 2;
        if (it0     < N_ITEM) out[(size_t)bi * N_ITEM + it0]     = acc0[bb] + out_bias[it0];
        if (it0 + 1 < N_ITEM) out[(size_t)bi * N_ITEM + it0 + 1] = acc1[bb] + out_bias[it0 + 1];
    }
}

extern "C" void kernel_launch(void* const* d_in, const int* in_sizes, int n_in,
                              void* d_out, int out_size, void* d_ws, size_t ws_size,
                              hipStream_t stream)
{
    const int*   e_src     = (const int*)d_in[0];          // edge_idx[0]
    const int*   e_dst     = e_src + NEDGE;                // edge_idx[1]
    const int*   e_type    = (const int*)d_in[1];
    const int*   seed_ids  = (const int*)d_in[2];
    const int*   seed_len  = (const int*)d_in[3];
    // d_in[4] = labels (unused)
    const float* basis     = (const float*)d_in[5];
    const float* att       = (const float*)d_in[6];
    const float* root      = (const float*)d_in[7];
    const float* rgcn_bias = (const float*)d_in[8];
    const float* attn_a    = (const float*)d_in[9];
    const float* attn_b    = (const float*)d_in[10];
    const float* out_bias  = (const float*)d_in[11];
    float*       out       = (float*)d_out;

    // workspace: [cnt | gcursor | aggr | deg]=memset-region, offs, cursor,
    // bucket, nodes, u   (~12 MB total)
    int*   cnt     = (int*)d_ws;
    int*   gcursor = cnt + CNT_PAD;
    float* aggr    = (float*)(gcursor + 16);
    float* deg     = aggr + (size_t)N_ITEM * DIM;
    int*   offs    = (int*)(deg + 6928);
    int*   cursor  = offs + OFFS_PAD;
    int*   bucket  = cursor + OFFS_PAD;
    float* nodes   = (float*)(bucket + NEDGE);
    float* u       = nodes + (size_t)N_ITEM * DIM;

    hipMemsetAsync(cnt, 0,
        (CNT_PAD + 16 + (size_t)N_ITEM * DIM + 6928) * sizeof(int), stream);

    count_kernel<<<(NEDGE + 255) / 256, 256, 0, stream>>>(e_src, e_dst, cnt);
    alloc_kernel<<<(N_ENTITY + 255) / 256, 256, 0, stream>>>(cnt, gcursor, offs, cursor);
    fill_kernel<<<(NEDGE + 255) / 256, 256, 0, stream>>>(
        e_src, e_dst, e_type, cursor, bucket, deg);
    aggregate_kernel<<<(N_ENTITY + 3) / 4, 256, 0, stream>>>(
        offs, cnt, bucket, basis, att, aggr);
    finalize_kernel<<<(N_ITEM * (DIM / 4) + 255) / 256, 256, 0, stream>>>(
        aggr, deg, root, rgcn_bias, nodes);
    pool_kernel<<<BATCH, 256, 0, stream>>>(
        nodes, seed_ids, seed_len, attn_a, attn_b, u);
    score_kernel<<<(N_ITEM + ITEM_TILE - 1) / ITEM_TILE, 256, 0, stream>>>(
        nodes, u, out_bias, out);
}